// Round 2
// baseline (212.814 us; speedup 1.0000x reference)
//
#include <hip/hip_runtime.h>
#include <hip/hip_bf16.h>
#include <stdint.h>
#include <stddef.h>

typedef __bf16 bf16_t;
typedef __bf16 bf16x8 __attribute__((ext_vector_type(8)));
typedef __bf16 bf16x4 __attribute__((ext_vector_type(4)));
typedef float floatx4 __attribute__((ext_vector_type(4)));

#define DIM 512
#define SEQ 4096
#define BATCH 8
#define LDP 40   // LDS pitch (elements): 80B rows -> 16B aligned, 2-way-max bank pattern

static __device__ __forceinline__ floatx4 mfma_bf16(bf16x8 a, bf16x8 b, floatx4 c) {
  return __builtin_amdgcn_mfma_f32_16x16x32_bf16(a, b, c, 0, 0, 0);
}

// ---------------- K0: w_qkv fp32 -> bf16 ----------------
__global__ __launch_bounds__(256) void k_cvt_w(const float* __restrict__ w, bf16_t* __restrict__ wb) {
  int i = (blockIdx.x * 256 + threadIdx.x) * 8;
  float4 a = *(const float4*)&w[i];
  float4 b = *(const float4*)&w[i + 4];
  bf16x8 o;
  o[0] = (bf16_t)a.x; o[1] = (bf16_t)a.y; o[2] = (bf16_t)a.z; o[3] = (bf16_t)a.w;
  o[4] = (bf16_t)b.x; o[5] = (bf16_t)b.y; o[6] = (bf16_t)b.z; o[7] = (bf16_t)b.w;
  *(bf16x8*)&wb[i] = o;
}

// ---------------- K1: qkv GEMM + fused softmax epilogues ----------------
// C[m, nn] = sum_k x[m,k] * wqkv[nn,k]; M=32768, N=1536, K=512
// n0<512: q-softmax over head (64 cols, wave-aligned), *0.125 -> qs bf16
// 512<=n0<1024: exp(k) -> ek bf16 + column sums S via atomics
// else: v -> vb bf16
__global__ __launch_bounds__(256) void k_qkv(const float* __restrict__ X,
                                             const bf16_t* __restrict__ Wb,
                                             bf16_t* __restrict__ qs,
                                             bf16_t* __restrict__ ek,
                                             bf16_t* __restrict__ vb,
                                             float* __restrict__ S) {
  __shared__ __align__(16) bf16_t As[128 * LDP];
  __shared__ __align__(16) bf16_t Bs[128 * LDP];
  const int tid = threadIdx.x;
  const int lane = tid & 63;
  const int wid = tid >> 6;
  const int wr = wid >> 1, wc = wid & 1;
  const int l15 = lane & 15, l4 = lane >> 4;
  const int m0 = blockIdx.x * 128;
  const int n0 = blockIdx.y * 128;

  floatx4 acc[4][4];
#pragma unroll
  for (int i = 0; i < 4; ++i)
#pragma unroll
    for (int j = 0; j < 4; ++j) acc[i][j] = (floatx4){0.f, 0.f, 0.f, 0.f};

  for (int kt = 0; kt < DIM; kt += 32) {
#pragma unroll
    for (int i = 0; i < 4; ++i) {
      int q = tid + i * 256;         // 1024 float4 chunks of A tile
      int row = q >> 3;
      int c4 = (q & 7) << 2;
      float4 f = *(const float4*)&X[(size_t)(m0 + row) * DIM + kt + c4];
      bf16x4 h;
      h[0] = (bf16_t)f.x; h[1] = (bf16_t)f.y; h[2] = (bf16_t)f.z; h[3] = (bf16_t)f.w;
      *(bf16x4*)&As[row * LDP + c4] = h;
    }
#pragma unroll
    for (int i = 0; i < 2; ++i) {
      int q = tid + i * 256;         // 512 8-elem chunks of B tile
      int row = q >> 2;
      int c8 = (q & 3) << 3;
      *(bf16x8*)&Bs[row * LDP + c8] = *(const bf16x8*)&Wb[(size_t)(n0 + row) * DIM + kt + c8];
    }
    __syncthreads();
    bf16x8 af[4], bfr[4];
#pragma unroll
    for (int f = 0; f < 4; ++f) {
      af[f]  = *(const bf16x8*)&As[(wr * 64 + f * 16 + l15) * LDP + l4 * 8];
      bfr[f] = *(const bf16x8*)&Bs[(wc * 64 + f * 16 + l15) * LDP + l4 * 8];
    }
#pragma unroll
    for (int i = 0; i < 4; ++i)
#pragma unroll
      for (int j = 0; j < 4; ++j)
        acc[i][j] = mfma_bf16(af[i], bfr[j], acc[i][j]);
    __syncthreads();
  }

  const int colbase = n0 + wc * 64;
  if (n0 < 512) {
    // q region: softmax over the wave's 64 cols (== one head), scale 1/8
#pragma unroll
    for (int fm = 0; fm < 4; ++fm) {
#pragma unroll
      for (int r = 0; r < 4; ++r) {
        float v0 = acc[fm][0][r], v1 = acc[fm][1][r], v2 = acc[fm][2][r], v3 = acc[fm][3][r];
        float mx = fmaxf(fmaxf(v0, v1), fmaxf(v2, v3));
        mx = fmaxf(mx, __shfl_xor(mx, 1));
        mx = fmaxf(mx, __shfl_xor(mx, 2));
        mx = fmaxf(mx, __shfl_xor(mx, 4));
        mx = fmaxf(mx, __shfl_xor(mx, 8));
        float e0 = __expf(v0 - mx), e1 = __expf(v1 - mx), e2 = __expf(v2 - mx), e3 = __expf(v3 - mx);
        float s = e0 + e1 + e2 + e3;
        s += __shfl_xor(s, 1); s += __shfl_xor(s, 2); s += __shfl_xor(s, 4); s += __shfl_xor(s, 8);
        float inv = 0.125f / s;
        int m = m0 + wr * 64 + fm * 16 + l4 * 4 + r;
        bf16_t* rowp = qs + (size_t)m * DIM + colbase;
        rowp[l15]      = (bf16_t)(e0 * inv);
        rowp[16 + l15] = (bf16_t)(e1 * inv);
        rowp[32 + l15] = (bf16_t)(e2 * inv);
        rowp[48 + l15] = (bf16_t)(e3 * inv);
      }
    }
  } else if (n0 < 1024) {
    const int cb = colbase - 512;
    float c0 = 0.f, c1 = 0.f, c2 = 0.f, c3 = 0.f;
#pragma unroll
    for (int fm = 0; fm < 4; ++fm) {
#pragma unroll
      for (int r = 0; r < 4; ++r) {
        int m = m0 + wr * 64 + fm * 16 + l4 * 4 + r;
        bf16_t* rowp = ek + (size_t)m * DIM + cb;
        float e0 = __expf(acc[fm][0][r]);
        float e1 = __expf(acc[fm][1][r]);
        float e2 = __expf(acc[fm][2][r]);
        float e3 = __expf(acc[fm][3][r]);
        rowp[l15]      = (bf16_t)e0;
        rowp[16 + l15] = (bf16_t)e1;
        rowp[32 + l15] = (bf16_t)e2;
        rowp[48 + l15] = (bf16_t)e3;
        c0 += e0; c1 += e1; c2 += e2; c3 += e3;
      }
    }
    // reduce over rows: across l4 groups
    c0 += __shfl_xor(c0, 16); c0 += __shfl_xor(c0, 32);
    c1 += __shfl_xor(c1, 16); c1 += __shfl_xor(c1, 32);
    c2 += __shfl_xor(c2, 16); c2 += __shfl_xor(c2, 32);
    c3 += __shfl_xor(c3, 16); c3 += __shfl_xor(c3, 32);
    if (lane < 16) {
      int b = m0 >> 12;
      atomicAdd(&S[b * 512 + cb + lane],      c0);
      atomicAdd(&S[b * 512 + cb + 16 + lane], c1);
      atomicAdd(&S[b * 512 + cb + 32 + lane], c2);
      atomicAdd(&S[b * 512 + cb + 48 + lane], c3);
    }
  } else {
    const int cb = colbase - 1024;
#pragma unroll
    for (int fm = 0; fm < 4; ++fm) {
#pragma unroll
      for (int r = 0; r < 4; ++r) {
        int m = m0 + wr * 64 + fm * 16 + l4 * 4 + r;
        bf16_t* rowp = vb + (size_t)m * DIM + cb;
        rowp[l15]      = (bf16_t)acc[fm][0][r];
        rowp[16 + l15] = (bf16_t)acc[fm][1][r];
        rowp[32 + l15] = (bf16_t)acc[fm][2][r];
        rowp[48 + l15] = (bf16_t)acc[fm][3][r];
      }
    }
  }
}

// ---------------- K2: ctxpart[b,h,chunk] = ek_chunk^T @ v_chunk (64x64) ----------------
#define TP 136
__global__ __launch_bounds__(256) void k_ctx(const bf16_t* __restrict__ ek,
                                             const bf16_t* __restrict__ vb,
                                             float* __restrict__ ctxpart) {
  __shared__ __align__(16) bf16_t ekT[64 * TP];
  __shared__ __align__(16) bf16_t vT[64 * TP];
  __shared__ float red[4096];
  const int tid = threadIdx.x;
  const int lane = tid & 63, wid = tid >> 6;
  const int l15 = lane & 15, l4 = lane >> 4;
  const int bh = blockIdx.x, chunk = blockIdx.y;
  const int b = bh >> 3, h = bh & 7;
  const int base = b * SEQ + chunk * 512;

  floatx4 acc[4][4];
#pragma unroll
  for (int i = 0; i < 4; ++i)
#pragma unroll
    for (int j = 0; j < 4; ++j) acc[i][j] = (floatx4){0.f, 0.f, 0.f, 0.f};

  for (int nt = 0; nt < 4; ++nt) {
    const int n0 = base + nt * 128;
    // stage transposed: [64 feat][128 n]
#pragma unroll
    for (int i = 0; i < 4; ++i) {
      int q = tid + i * 256;
      int n = q & 127;
      int c8 = (q >> 7) << 3;
      bf16x8 vk = *(const bf16x8*)&ek[(size_t)(n0 + n) * DIM + h * 64 + c8];
      bf16x8 vv = *(const bf16x8*)&vb[(size_t)(n0 + n) * DIM + h * 64 + c8];
#pragma unroll
      for (int j = 0; j < 8; ++j) {
        ekT[(c8 + j) * TP + n] = vk[j];
        vT [(c8 + j) * TP + n] = vv[j];
      }
    }
    __syncthreads();
    const int nb = wid * 32;   // each wave takes a disjoint K=32 slice
    bf16x8 af[4], bfr[4];
#pragma unroll
    for (int f = 0; f < 4; ++f) {
      af[f]  = *(const bf16x8*)&ekT[(f * 16 + l15) * TP + nb + l4 * 8];
      bfr[f] = *(const bf16x8*)&vT [(f * 16 + l15) * TP + nb + l4 * 8];
    }
#pragma unroll
    for (int i = 0; i < 4; ++i)
#pragma unroll
      for (int j = 0; j < 4; ++j)
        acc[i][j] = mfma_bf16(af[i], bfr[j], acc[i][j]);
    __syncthreads();
  }

  // deterministic cross-wave reduce
  for (int w = 0; w < 4; ++w) {
    if (wid == w) {
#pragma unroll
      for (int fm = 0; fm < 4; ++fm)
#pragma unroll
        for (int fn = 0; fn < 4; ++fn)
#pragma unroll
          for (int r = 0; r < 4; ++r) {
            int d = fm * 16 + l4 * 4 + r;
            int e = fn * 16 + l15;
            if (w == 0) red[d * 64 + e] = acc[fm][fn][r];
            else        red[d * 64 + e] += acc[fm][fn][r];
          }
    }
    __syncthreads();
  }
  float* dst = ctxpart + ((size_t)bh * 8 + chunk) * 4096;
#pragma unroll
  for (int i = 0; i < 4; ++i) {
    int q = tid + i * 256;
    *(float4*)&dst[q * 4] = *(const float4*)&red[q * 4];
  }
}

// ---------------- K3a: reduce partials + divide by column sums ----------------
__global__ __launch_bounds__(256) void k_ctxred(const float* __restrict__ ctxpart,
                                                const float* __restrict__ S,
                                                float* __restrict__ ctx) {
  int bh = blockIdx.x;
  int idx = blockIdx.y * 256 + threadIdx.x;
  int b = bh >> 3, h = bh & 7;
  float s = 0.f;
#pragma unroll
  for (int p = 0; p < 8; ++p) s += ctxpart[((size_t)bh * 8 + p) * 4096 + idx];
  int d = idx >> 6;
  ctx[(size_t)bh * 4096 + idx] = s / S[b * 512 + h * 64 + d];
}

// ---------------- K3b: Mt[b][dcol][h*64+d] = sum_e ctx[b,h,d,e]*w_out[dcol,h*64+e] ----------------
__global__ __launch_bounds__(128) void k_mt(const float* __restrict__ ctx,
                                            const float* __restrict__ w_out,
                                            bf16_t* __restrict__ Mt) {
  __shared__ float cs[4096];
  const int tid = threadIdx.x;
  const int b = blockIdx.x, h = blockIdx.y, dq = blockIdx.z;
#pragma unroll
  for (int i = 0; i < 8; ++i) {
    int q = tid + i * 128;
    *(float4*)&cs[q * 4] = *(const float4*)&ctx[((size_t)(b * 8 + h)) * 4096 + q * 4];
  }
  __syncthreads();
  const int dcol = dq * 128 + tid;
  float a[64];
#pragma unroll
  for (int d = 0; d < 64; ++d) a[d] = 0.f;
  for (int e = 0; e < 64; ++e) {
    float we = w_out[(size_t)dcol * 512 + h * 64 + e];
#pragma unroll
    for (int d = 0; d < 64; ++d) a[d] += cs[d * 64 + e] * we;
  }
  bf16_t* dst = Mt + ((size_t)b * 512 + dcol) * 512 + h * 64;
#pragma unroll
  for (int g = 0; g < 8; ++g) {
    bf16x8 o;
#pragma unroll
    for (int j = 0; j < 8; ++j) o[j] = (bf16_t)a[g * 8 + j];
    *(bf16x8*)&dst[g * 8] = o;
  }
}

// ---------------- K4: out2[b] = qs[b] @ Mt[b]^T(bt) ----------------
__global__ __launch_bounds__(256) void k_out(const bf16_t* __restrict__ qs,
                                             const bf16_t* __restrict__ Mt,
                                             float* __restrict__ out2) {
  __shared__ __align__(16) bf16_t As[128 * LDP];
  __shared__ __align__(16) bf16_t Bs[128 * LDP];
  const int tid = threadIdx.x;
  const int lane = tid & 63, wid = tid >> 6;
  const int wr = wid >> 1, wc = wid & 1;
  const int l15 = lane & 15, l4 = lane >> 4;
  const int m0 = blockIdx.x * 128;
  const int n0 = blockIdx.y * 128;
  const bf16_t* Bp = Mt + (size_t)(blockIdx.x >> 5) * 512 * 512;

  floatx4 acc[4][4];
#pragma unroll
  for (int i = 0; i < 4; ++i)
#pragma unroll
    for (int j = 0; j < 4; ++j) acc[i][j] = (floatx4){0.f, 0.f, 0.f, 0.f};

  for (int kt = 0; kt < 512; kt += 32) {
#pragma unroll
    for (int i = 0; i < 2; ++i) {
      int q = tid + i * 256;
      int row = q >> 2;
      int c8 = (q & 3) << 3;
      *(bf16x8*)&As[row * LDP + c8] = *(const bf16x8*)&qs[(size_t)(m0 + row) * 512 + kt + c8];
      *(bf16x8*)&Bs[row * LDP + c8] = *(const bf16x8*)&Bp[(size_t)(n0 + row) * 512 + kt + c8];
    }
    __syncthreads();
    bf16x8 af[4], bfr[4];
#pragma unroll
    for (int f = 0; f < 4; ++f) {
      af[f]  = *(const bf16x8*)&As[(wr * 64 + f * 16 + l15) * LDP + l4 * 8];
      bfr[f] = *(const bf16x8*)&Bs[(wc * 64 + f * 16 + l15) * LDP + l4 * 8];
    }
#pragma unroll
    for (int i = 0; i < 4; ++i)
#pragma unroll
      for (int j = 0; j < 4; ++j)
        acc[i][j] = mfma_bf16(af[i], bfr[j], acc[i][j]);
    __syncthreads();
  }
#pragma unroll
  for (int fm = 0; fm < 4; ++fm) {
#pragma unroll
    for (int r = 0; r < 4; ++r) {
      int m = m0 + wr * 64 + fm * 16 + l4 * 4 + r;
      float* rowp = out2 + (size_t)m * 512 + n0 + wc * 64;
      rowp[l15]      = acc[fm][0][r];
      rowp[16 + l15] = acc[fm][1][r];
      rowp[32 + l15] = acc[fm][2][r];
      rowp[48 + l15] = acc[fm][3][r];
    }
  }
}

// ---------------- K5: gamma LayerNorm, wave per row ----------------
__global__ __launch_bounds__(256) void k_ln(const float* __restrict__ out2,
                                            const float* __restrict__ gamma,
                                            float* __restrict__ out) {
  const int lane = threadIdx.x & 63;
  const int row = blockIdx.x * 4 + (threadIdx.x >> 6);
  const float* x = out2 + (size_t)row * 512;
  float4 v0 = ((const float4*)x)[lane];
  float4 v1 = ((const float4*)x)[lane + 64];
  float s = v0.x + v0.y + v0.z + v0.w + v1.x + v1.y + v1.z + v1.w;
  float q = v0.x * v0.x + v0.y * v0.y + v0.z * v0.z + v0.w * v0.w
          + v1.x * v1.x + v1.y * v1.y + v1.z * v1.z + v1.w * v1.w;
#pragma unroll
  for (int m = 1; m <= 32; m <<= 1) { s += __shfl_xor(s, m); q += __shfl_xor(q, m); }
  float mean = s * (1.f / 512.f);
  float var = q * (1.f / 512.f) - mean * mean;
  float rstd = rsqrtf(var + 1e-5f);
  float4 g0 = ((const float4*)gamma)[lane];
  float4 g1 = ((const float4*)gamma)[lane + 64];
  float4 o0, o1;
  o0.x = (v0.x - mean) * rstd * g0.x;
  o0.y = (v0.y - mean) * rstd * g0.y;
  o0.z = (v0.z - mean) * rstd * g0.z;
  o0.w = (v0.w - mean) * rstd * g0.w;
  o1.x = (v1.x - mean) * rstd * g1.x;
  o1.y = (v1.y - mean) * rstd * g1.y;
  o1.z = (v1.z - mean) * rstd * g1.z;
  o1.w = (v1.w - mean) * rstd * g1.w;
  float* y = out + (size_t)row * 512;
  ((float4*)y)[lane] = o0;
  ((float4*)y)[lane + 64] = o1;
}

extern "C" void kernel_launch(void* const* d_in, const int* in_sizes, int n_in,
                              void* d_out, int out_size, void* d_ws, size_t ws_size,
                              hipStream_t stream) {
  const float* x     = (const float*)d_in[0];
  const float* w_qkv = (const float*)d_in[1];
  const float* w_out = (const float*)d_in[2];
  const float* gamma = (const float*)d_in[3];
  float* out = (float*)d_out;
  char* ws = (char*)d_ws;

  // workspace layout (bytes)
  bf16_t* qs      = (bf16_t*)(ws);                       // 33,554,432
  bf16_t* ek      = (bf16_t*)(ws + 33554432);            // 33,554,432
  bf16_t* vb      = (bf16_t*)(ws + 67108864);            // 33,554,432
  bf16_t* wqkvb   = (bf16_t*)(ws + 100663296);           //  1,572,864
  float*  S       = (float*)(ws + 102236160);            //     16,384
  float*  ctx     = (float*)(ws + 102252544);            //  1,048,576
  float*  ctxpart = (float*)(ws + 103301120);            //  8,388,608
  bf16_t* Mt      = (bf16_t*)(ws + 111689728);           //  4,194,304  (end 115,884,032)
  float*  out2    = (float*)(ws + 33554432);             // aliases ek+vb (consumed before K4)

  hipMemsetAsync(S, 0, BATCH * 512 * sizeof(float), stream);

  k_cvt_w<<<384, 256, 0, stream>>>(w_qkv, wqkvb);

  dim3 g1(256, 12);
  k_qkv<<<g1, 256, 0, stream>>>(x, wqkvb, qs, ek, vb, S);

  dim3 g2(64, 8);
  k_ctx<<<g2, 256, 0, stream>>>(ek, vb, ctxpart);

  dim3 g3(64, 16);
  k_ctxred<<<g3, 256, 0, stream>>>(ctxpart, S, ctx);

  dim3 g4(8, 8, 4);
  k_mt<<<g4, 128, 0, stream>>>(ctx, w_out, Mt);

  dim3 g5(256, 4);
  k_out<<<g5, 256, 0, stream>>>(qs, Mt, out2);

  k_ln<<<8192, 256, 0, stream>>>(out2, gamma, out);
}

// Round 3
// 203.586 us; speedup vs baseline: 1.0453x; 1.0453x over previous
//
#include <hip/hip_runtime.h>
#include <hip/hip_bf16.h>
#include <stdint.h>
#include <stddef.h>

typedef __bf16 bf16_t;
typedef __bf16 bf16x8 __attribute__((ext_vector_type(8)));
typedef __bf16 bf16x4 __attribute__((ext_vector_type(4)));
typedef float floatx4 __attribute__((ext_vector_type(4)));

#define DIM 512
#define SEQ 4096
#define BATCH 8
#define BK 32
#define LDP 40   // padded pitch for k_ctx staging (unchanged path)

static __device__ __forceinline__ floatx4 mfma_bf16(bf16x8 a, bf16x8 b, floatx4 c) {
  return __builtin_amdgcn_mfma_f32_16x16x32_bf16(a, b, c, 0, 0, 0);
}

typedef __attribute__((address_space(1))) const void* gas_ptr;
typedef __attribute__((address_space(3))) void* las_ptr;
static __device__ __forceinline__ void gll16(const void* g, void* l) {
  __builtin_amdgcn_global_load_lds((gas_ptr)g, (las_ptr)l, 16, 0, 0);
}

// ---------------- K0: w_qkv fp32 -> bf16 ----------------
__global__ __launch_bounds__(256) void k_cvt_w(const float* __restrict__ w, bf16_t* __restrict__ wb) {
  int i = (blockIdx.x * 256 + threadIdx.x) * 8;
  float4 a = *(const float4*)&w[i];
  float4 b = *(const float4*)&w[i + 4];
  bf16x8 o;
  o[0] = (bf16_t)a.x; o[1] = (bf16_t)a.y; o[2] = (bf16_t)a.z; o[3] = (bf16_t)a.w;
  o[4] = (bf16_t)b.x; o[5] = (bf16_t)b.y; o[6] = (bf16_t)b.z; o[7] = (bf16_t)b.w;
  *(bf16x8*)&wb[i] = o;
}

// ---------------- K1: qkv GEMM (global_load_lds staged) + fused epilogues ----------------
// A tile: fp32 [128][32] in LDS, unit=4 floats(16B), swizzle u^=(row&7)
// B tile: bf16 [128][32] in LDS, unit=8 bf16 (16B), swizzle u^=(row&3)
__global__ __launch_bounds__(256) void k_qkv(const float* __restrict__ X,
                                             const bf16_t* __restrict__ Wb,
                                             bf16_t* __restrict__ qs,
                                             bf16_t* __restrict__ ek,
                                             bf16_t* __restrict__ vb,
                                             float* __restrict__ S) {
  __shared__ __align__(16) float  Asf[128 * BK];  // 16 KB
  __shared__ __align__(16) bf16_t Bs [128 * BK];  //  8 KB
  const int tid = threadIdx.x;
  const int lane = tid & 63;
  const int w = tid >> 6;
  const int wr = w >> 1, wc = w & 1;
  const int l15 = lane & 15, l4 = lane >> 4;
  const int m0 = blockIdx.x * 128;
  const int n0 = blockIdx.y * 128;

  // A staging: 4 issues x (8 rows, lane: row=lane>>3, unit=lane&7), pre-swizzled source
  const float* gA = X + (size_t)(m0 + w * 32 + (lane >> 3)) * DIM
                      + (((lane & 7) ^ (lane >> 3)) << 2);
  // B staging: 2 issues x (16 rows, lane: row=lane>>2, unit=lane&3), pre-swizzled source
  const bf16_t* gB = Wb + (size_t)(n0 + w * 32 + (lane >> 2)) * DIM
                        + ((((lane & 3) ^ ((lane >> 2) & 3))) << 3);
  float*  lA = &Asf[(w * 32) * BK];
  bf16_t* lB = &Bs [(w * 32) * BK];

  floatx4 acc[4][4];
#pragma unroll
  for (int i = 0; i < 4; ++i)
#pragma unroll
    for (int j = 0; j < 4; ++j) acc[i][j] = (floatx4){0.f, 0.f, 0.f, 0.f};

  for (int kt = 0; kt < DIM; kt += BK) {
    gll16(gA,            lA);
    gll16(gA + 8 * DIM,  lA + 8 * BK);
    gll16(gA + 16 * DIM, lA + 16 * BK);
    gll16(gA + 24 * DIM, lA + 24 * BK);
    gll16(gB,            lB);
    gll16(gB + 16 * DIM, lB + 16 * BK);
    gA += BK; gB += BK;
    __syncthreads();
    bf16x8 af[4], bfr[4];
#pragma unroll
    for (int f = 0; f < 4; ++f) {
      int ar = wr * 64 + f * 16 + l15;
      int u0 = (l4 * 2) ^ (ar & 7);
      int u1 = (l4 * 2 + 1) ^ (ar & 7);
      float4 a0 = *(const float4*)&Asf[ar * BK + u0 * 4];
      float4 a1 = *(const float4*)&Asf[ar * BK + u1 * 4];
      bf16x8 t;
      t[0] = (bf16_t)a0.x; t[1] = (bf16_t)a0.y; t[2] = (bf16_t)a0.z; t[3] = (bf16_t)a0.w;
      t[4] = (bf16_t)a1.x; t[5] = (bf16_t)a1.y; t[6] = (bf16_t)a1.z; t[7] = (bf16_t)a1.w;
      af[f] = t;
      int br = wc * 64 + f * 16 + l15;
      int bu = l4 ^ (br & 3);
      bfr[f] = *(const bf16x8*)&Bs[br * BK + bu * 8];
    }
#pragma unroll
    for (int i = 0; i < 4; ++i)
#pragma unroll
      for (int j = 0; j < 4; ++j)
        acc[i][j] = mfma_bf16(af[i], bfr[j], acc[i][j]);
    __syncthreads();
  }

  const int colbase = n0 + wc * 64;
  if (n0 < 512) {
    // q region: softmax over the wave's 64 cols (== one head), scale 1/8
#pragma unroll
    for (int fm = 0; fm < 4; ++fm) {
#pragma unroll
      for (int r = 0; r < 4; ++r) {
        float v0 = acc[fm][0][r], v1 = acc[fm][1][r], v2 = acc[fm][2][r], v3 = acc[fm][3][r];
        float mx = fmaxf(fmaxf(v0, v1), fmaxf(v2, v3));
        mx = fmaxf(mx, __shfl_xor(mx, 1));
        mx = fmaxf(mx, __shfl_xor(mx, 2));
        mx = fmaxf(mx, __shfl_xor(mx, 4));
        mx = fmaxf(mx, __shfl_xor(mx, 8));
        float e0 = __expf(v0 - mx), e1 = __expf(v1 - mx), e2 = __expf(v2 - mx), e3 = __expf(v3 - mx);
        float s = e0 + e1 + e2 + e3;
        s += __shfl_xor(s, 1); s += __shfl_xor(s, 2); s += __shfl_xor(s, 4); s += __shfl_xor(s, 8);
        float inv = 0.125f / s;
        int m = m0 + wr * 64 + fm * 16 + l4 * 4 + r;
        bf16_t* rowp = qs + (size_t)m * DIM + colbase;
        rowp[l15]      = (bf16_t)(e0 * inv);
        rowp[16 + l15] = (bf16_t)(e1 * inv);
        rowp[32 + l15] = (bf16_t)(e2 * inv);
        rowp[48 + l15] = (bf16_t)(e3 * inv);
      }
    }
  } else if (n0 < 1024) {
    const int cb = colbase - 512;
    float c0 = 0.f, c1 = 0.f, c2 = 0.f, c3 = 0.f;
#pragma unroll
    for (int fm = 0; fm < 4; ++fm) {
#pragma unroll
      for (int r = 0; r < 4; ++r) {
        int m = m0 + wr * 64 + fm * 16 + l4 * 4 + r;
        bf16_t* rowp = ek + (size_t)m * DIM + cb;
        float e0 = __expf(acc[fm][0][r]);
        float e1 = __expf(acc[fm][1][r]);
        float e2 = __expf(acc[fm][2][r]);
        float e3 = __expf(acc[fm][3][r]);
        rowp[l15]      = (bf16_t)e0;
        rowp[16 + l15] = (bf16_t)e1;
        rowp[32 + l15] = (bf16_t)e2;
        rowp[48 + l15] = (bf16_t)e3;
        c0 += e0; c1 += e1; c2 += e2; c3 += e3;
      }
    }
    c0 += __shfl_xor(c0, 16); c0 += __shfl_xor(c0, 32);
    c1 += __shfl_xor(c1, 16); c1 += __shfl_xor(c1, 32);
    c2 += __shfl_xor(c2, 16); c2 += __shfl_xor(c2, 32);
    c3 += __shfl_xor(c3, 16); c3 += __shfl_xor(c3, 32);
    if (lane < 16) {
      int b = m0 >> 12;
      atomicAdd(&S[b * 512 + cb + lane],      c0);
      atomicAdd(&S[b * 512 + cb + 16 + lane], c1);
      atomicAdd(&S[b * 512 + cb + 32 + lane], c2);
      atomicAdd(&S[b * 512 + cb + 48 + lane], c3);
    }
  } else {
    const int cb = colbase - 1024;
#pragma unroll
    for (int fm = 0; fm < 4; ++fm) {
#pragma unroll
      for (int r = 0; r < 4; ++r) {
        int m = m0 + wr * 64 + fm * 16 + l4 * 4 + r;
        bf16_t* rowp = vb + (size_t)m * DIM + cb;
        rowp[l15]      = (bf16_t)acc[fm][0][r];
        rowp[16 + l15] = (bf16_t)acc[fm][1][r];
        rowp[32 + l15] = (bf16_t)acc[fm][2][r];
        rowp[48 + l15] = (bf16_t)acc[fm][3][r];
      }
    }
  }
}

// ---------------- K2: ctxpart[b,h,chunk] = ek_chunk^T @ v_chunk (64x64) ----------------
#define TP 136
__global__ __launch_bounds__(256) void k_ctx(const bf16_t* __restrict__ ek,
                                             const bf16_t* __restrict__ vb,
                                             float* __restrict__ ctxpart) {
  __shared__ __align__(16) bf16_t ekT[64 * TP];
  __shared__ __align__(16) bf16_t vT[64 * TP];
  __shared__ float red[4096];
  const int tid = threadIdx.x;
  const int lane = tid & 63, wid = tid >> 6;
  const int l15 = lane & 15, l4 = lane >> 4;
  const int bh = blockIdx.x, chunk = blockIdx.y;
  const int b = bh >> 3, h = bh & 7;
  const int base = b * SEQ + chunk * 512;

  floatx4 acc[4][4];
#pragma unroll
  for (int i = 0; i < 4; ++i)
#pragma unroll
    for (int j = 0; j < 4; ++j) acc[i][j] = (floatx4){0.f, 0.f, 0.f, 0.f};

  for (int nt = 0; nt < 4; ++nt) {
    const int n0 = base + nt * 128;
#pragma unroll
    for (int i = 0; i < 4; ++i) {
      int q = tid + i * 256;
      int n = q & 127;
      int c8 = (q >> 7) << 3;
      bf16x8 vk = *(const bf16x8*)&ek[(size_t)(n0 + n) * DIM + h * 64 + c8];
      bf16x8 vv = *(const bf16x8*)&vb[(size_t)(n0 + n) * DIM + h * 64 + c8];
#pragma unroll
      for (int j = 0; j < 8; ++j) {
        ekT[(c8 + j) * TP + n] = vk[j];
        vT [(c8 + j) * TP + n] = vv[j];
      }
    }
    __syncthreads();
    const int nb = wid * 32;
    bf16x8 af[4], bfr[4];
#pragma unroll
    for (int f = 0; f < 4; ++f) {
      af[f]  = *(const bf16x8*)&ekT[(f * 16 + l15) * TP + nb + l4 * 8];
      bfr[f] = *(const bf16x8*)&vT [(f * 16 + l15) * TP + nb + l4 * 8];
    }
#pragma unroll
    for (int i = 0; i < 4; ++i)
#pragma unroll
      for (int j = 0; j < 4; ++j)
        acc[i][j] = mfma_bf16(af[i], bfr[j], acc[i][j]);
    __syncthreads();
  }

  for (int w = 0; w < 4; ++w) {
    if (wid == w) {
#pragma unroll
      for (int fm = 0; fm < 4; ++fm)
#pragma unroll
        for (int fn = 0; fn < 4; ++fn)
#pragma unroll
          for (int r = 0; r < 4; ++r) {
            int d = fm * 16 + l4 * 4 + r;
            int e = fn * 16 + l15;
            if (w == 0) red[d * 64 + e] = acc[fm][fn][r];
            else        red[d * 64 + e] += acc[fm][fn][r];
          }
    }
    __syncthreads();
  }
  float* dst = ctxpart + ((size_t)bh * 8 + chunk) * 4096;
#pragma unroll
  for (int i = 0; i < 4; ++i) {
    int q = tid + i * 256;
    *(float4*)&dst[q * 4] = *(const float4*)&red[q * 4];
  }
}

// ---------------- K3a: reduce partials + divide by column sums ----------------
__global__ __launch_bounds__(256) void k_ctxred(const float* __restrict__ ctxpart,
                                                const float* __restrict__ S,
                                                float* __restrict__ ctx) {
  int bh = blockIdx.x;
  int idx = blockIdx.y * 256 + threadIdx.x;
  int b = bh >> 3, h = bh & 7;
  float s = 0.f;
#pragma unroll
  for (int p = 0; p < 8; ++p) s += ctxpart[((size_t)bh * 8 + p) * 4096 + idx];
  int d = idx >> 6;
  ctx[(size_t)bh * 4096 + idx] = s / S[b * 512 + h * 64 + d];
}

// ---------------- K3b: Mt[b][dcol][h*64+d] = sum_e ctx[b,h,d,e]*w_out[dcol,h*64+e] ----------------
__global__ __launch_bounds__(128) void k_mt(const float* __restrict__ ctx,
                                            const float* __restrict__ w_out,
                                            bf16_t* __restrict__ Mt) {
  __shared__ float cs[4096];
  const int tid = threadIdx.x;
  const int b = blockIdx.x, h = blockIdx.y, dq = blockIdx.z;
#pragma unroll
  for (int i = 0; i < 8; ++i) {
    int q = tid + i * 128;
    *(float4*)&cs[q * 4] = *(const float4*)&ctx[((size_t)(b * 8 + h)) * 4096 + q * 4];
  }
  __syncthreads();
  const int dcol = dq * 128 + tid;
  float a[64];
#pragma unroll
  for (int d = 0; d < 64; ++d) a[d] = 0.f;
  for (int e = 0; e < 64; ++e) {
    float we = w_out[(size_t)dcol * 512 + h * 64 + e];
#pragma unroll
    for (int d = 0; d < 64; ++d) a[d] += cs[d * 64 + e] * we;
  }
  bf16_t* dst = Mt + ((size_t)b * 512 + dcol) * 512 + h * 64;
#pragma unroll
  for (int g = 0; g < 8; ++g) {
    bf16x8 o;
#pragma unroll
    for (int j = 0; j < 8; ++j) o[j] = (bf16_t)a[g * 8 + j];
    *(bf16x8*)&dst[g * 8] = o;
  }
}

// ---------------- K4: out2[b] = qs[b] @ Mt[b] (both bf16, global_load_lds staged) ----------------
__global__ __launch_bounds__(256) void k_out(const bf16_t* __restrict__ qs,
                                             const bf16_t* __restrict__ Mt,
                                             float* __restrict__ out2) {
  __shared__ __align__(16) bf16_t As2[128 * BK];
  __shared__ __align__(16) bf16_t Bs2[128 * BK];
  const int tid = threadIdx.x;
  const int lane = tid & 63, w = tid >> 6;
  const int wr = w >> 1, wc = w & 1;
  const int l15 = lane & 15, l4 = lane >> 4;
  const int m0 = blockIdx.x * 128;
  const int n0 = blockIdx.y * 128;
  const bf16_t* Bp = Mt + (size_t)(blockIdx.x >> 5) * 512 * 512;

  const int srow = lane >> 2;
  const int sunit = (lane & 3) ^ (srow & 3);
  const bf16_t* gA = qs + (size_t)(m0 + w * 32 + srow) * 512 + (sunit << 3);
  const bf16_t* gB = Bp + (size_t)(n0 + w * 32 + srow) * 512 + (sunit << 3);
  bf16_t* lA = &As2[(w * 32) * BK];
  bf16_t* lB = &Bs2[(w * 32) * BK];

  floatx4 acc[4][4];
#pragma unroll
  for (int i = 0; i < 4; ++i)
#pragma unroll
    for (int j = 0; j < 4; ++j) acc[i][j] = (floatx4){0.f, 0.f, 0.f, 0.f};

  for (int kt = 0; kt < 512; kt += BK) {
    gll16(gA,            lA);
    gll16(gA + 16 * 512, lA + 16 * BK);
    gll16(gB,            lB);
    gll16(gB + 16 * 512, lB + 16 * BK);
    gA += BK; gB += BK;
    __syncthreads();
    bf16x8 af[4], bfr[4];
#pragma unroll
    for (int f = 0; f < 4; ++f) {
      int ar = wr * 64 + f * 16 + l15;
      int au = l4 ^ (ar & 3);
      af[f] = *(const bf16x8*)&As2[ar * BK + au * 8];
      int br = wc * 64 + f * 16 + l15;
      int bu = l4 ^ (br & 3);
      bfr[f] = *(const bf16x8*)&Bs2[br * BK + bu * 8];
    }
#pragma unroll
    for (int i = 0; i < 4; ++i)
#pragma unroll
      for (int j = 0; j < 4; ++j)
        acc[i][j] = mfma_bf16(af[i], bfr[j], acc[i][j]);
    __syncthreads();
  }
#pragma unroll
  for (int fm = 0; fm < 4; ++fm) {
#pragma unroll
    for (int r = 0; r < 4; ++r) {
      int m = m0 + wr * 64 + fm * 16 + l4 * 4 + r;
      float* rowp = out2 + (size_t)m * 512 + n0 + wc * 64;
      rowp[l15]      = acc[fm][0][r];
      rowp[16 + l15] = acc[fm][1][r];
      rowp[32 + l15] = acc[fm][2][r];
      rowp[48 + l15] = acc[fm][3][r];
    }
  }
}

// ---------------- K5: gamma LayerNorm, wave per row ----------------
__global__ __launch_bounds__(256) void k_ln(const float* __restrict__ out2,
                                            const float* __restrict__ gamma,
                                            float* __restrict__ out) {
  const int lane = threadIdx.x & 63;
  const int row = blockIdx.x * 4 + (threadIdx.x >> 6);
  const float* x = out2 + (size_t)row * 512;
  float4 v0 = ((const float4*)x)[lane];
  float4 v1 = ((const float4*)x)[lane + 64];
  float s = v0.x + v0.y + v0.z + v0.w + v1.x + v1.y + v1.z + v1.w;
  float q = v0.x * v0.x + v0.y * v0.y + v0.z * v0.z + v0.w * v0.w
          + v1.x * v1.x + v1.y * v1.y + v1.z * v1.z + v1.w * v1.w;
#pragma unroll
  for (int m = 1; m <= 32; m <<= 1) { s += __shfl_xor(s, m); q += __shfl_xor(q, m); }
  float mean = s * (1.f / 512.f);
  float var = q * (1.f / 512.f) - mean * mean;
  float rstd = rsqrtf(var + 1e-5f);
  float4 g0 = ((const float4*)gamma)[lane];
  float4 g1 = ((const float4*)gamma)[lane + 64];
  float4 o0, o1;
  o0.x = (v0.x - mean) * rstd * g0.x;
  o0.y = (v0.y - mean) * rstd * g0.y;
  o0.z = (v0.z - mean) * rstd * g0.z;
  o0.w = (v0.w - mean) * rstd * g0.w;
  o1.x = (v1.x - mean) * rstd * g1.x;
  o1.y = (v1.y - mean) * rstd * g1.y;
  o1.z = (v1.z - mean) * rstd * g1.z;
  o1.w = (v1.w - mean) * rstd * g1.w;
  float* y = out + (size_t)row * 512;
  ((float4*)y)[lane] = o0;
  ((float4*)y)[lane + 64] = o1;
}

extern "C" void kernel_launch(void* const* d_in, const int* in_sizes, int n_in,
                              void* d_out, int out_size, void* d_ws, size_t ws_size,
                              hipStream_t stream) {
  const float* x     = (const float*)d_in[0];
  const float* w_qkv = (const float*)d_in[1];
  const float* w_out = (const float*)d_in[2];
  const float* gamma = (const float*)d_in[3];
  float* out = (float*)d_out;
  char* ws = (char*)d_ws;

  bf16_t* qs      = (bf16_t*)(ws);                       // 33,554,432
  bf16_t* ek      = (bf16_t*)(ws + 33554432);            // 33,554,432
  bf16_t* vb      = (bf16_t*)(ws + 67108864);            // 33,554,432
  bf16_t* wqkvb   = (bf16_t*)(ws + 100663296);           //  1,572,864
  float*  S       = (float*)(ws + 102236160);            //     16,384
  float*  ctx     = (float*)(ws + 102252544);            //  1,048,576
  float*  ctxpart = (float*)(ws + 103301120);            //  8,388,608
  bf16_t* Mt      = (bf16_t*)(ws + 111689728);           //  4,194,304
  float*  out2    = (float*)(ws + 33554432);             // aliases ek+vb (consumed before K4)

  hipMemsetAsync(S, 0, BATCH * 512 * sizeof(float), stream);

  k_cvt_w<<<384, 256, 0, stream>>>(w_qkv, wqkvb);

  dim3 g1(256, 12);
  k_qkv<<<g1, 256, 0, stream>>>(x, wqkvb, qs, ek, vb, S);

  dim3 g2(64, 8);
  k_ctx<<<g2, 256, 0, stream>>>(ek, vb, ctxpart);

  dim3 g3(64, 16);
  k_ctxred<<<g3, 256, 0, stream>>>(ctxpart, S, ctx);

  dim3 g4(8, 8, 4);
  k_mt<<<g4, 128, 0, stream>>>(ctx, w_out, Mt);

  dim3 g5(256, 4);
  k_out<<<g5, 256, 0, stream>>>(qs, Mt, out2);

  k_ln<<<8192, 256, 0, stream>>>(out2, gamma, out);
}

// Round 5
// 198.807 us; speedup vs baseline: 1.0705x; 1.0240x over previous
//
#include <hip/hip_runtime.h>
#include <hip/hip_bf16.h>
#include <stdint.h>
#include <stddef.h>

typedef __bf16 bf16_t;
typedef __bf16 bf16x8 __attribute__((ext_vector_type(8)));
typedef float floatx4 __attribute__((ext_vector_type(4)));

#define DIM 512
#define SEQ 4096
#define BATCH 8

static __device__ __forceinline__ floatx4 mfma_bf16(bf16x8 a, bf16x8 b, floatx4 c) {
  return __builtin_amdgcn_mfma_f32_16x16x32_bf16(a, b, c, 0, 0, 0);
}

typedef __attribute__((address_space(1))) const void* gas_ptr;
typedef __attribute__((address_space(3))) void* las_ptr;
static __device__ __forceinline__ void gll16(const void* g, void* l) {
  __builtin_amdgcn_global_load_lds((gas_ptr)g, (las_ptr)l, 16, 0, 0);
}

// ---------------- K0: fp32 -> bf16 converter (used for w_qkv and x) ----------------
__global__ __launch_bounds__(256) void k_cvt(const float* __restrict__ w, bf16_t* __restrict__ wb) {
  int i = (blockIdx.x * 256 + threadIdx.x) * 8;
  float4 a = *(const float4*)&w[i];
  float4 b = *(const float4*)&w[i + 4];
  bf16x8 o;
  o[0] = (bf16_t)a.x; o[1] = (bf16_t)a.y; o[2] = (bf16_t)a.z; o[3] = (bf16_t)a.w;
  o[4] = (bf16_t)b.x; o[5] = (bf16_t)b.y; o[6] = (bf16_t)b.z; o[7] = (bf16_t)b.w;
  *(bf16x8*)&wb[i] = o;
}

// ---------------- K1: qkv GEMM (BK=64, gll-staged, ^(row&7) swizzle) + fused epilogues ----------------
// XB=true: A from Xb (bf16). XB=false: A from X (fp32, converted per-fragment).
// LDS layout A(bf16): elem (r, k) at r*64 + ((k>>3)^(r&7))*8 + (k&7); fp32: 16B-unit u at u^(r&7).
template<bool XB>
__global__ __launch_bounds__(256) void k_qkv(const float* __restrict__ X,
                                             const bf16_t* __restrict__ Xb,
                                             const bf16_t* __restrict__ Wb,
                                             bf16_t* __restrict__ qs,
                                             bf16_t* __restrict__ ek,
                                             bf16_t* __restrict__ vb,
                                             float* __restrict__ S) {
  __shared__ __align__(16) char Abuf[XB ? (128 * 64 * 2) : (128 * 64 * 4)];
  __shared__ __align__(16) bf16_t Bs[128 * 64];
  const int tid = threadIdx.x;
  const int lane = tid & 63;
  const int w = tid >> 6;
  const int wr = w >> 1, wc = w & 1;
  const int l15 = lane & 15, l4 = lane >> 4;
  const int m0 = blockIdx.x * 128;
  const int n0 = blockIdx.y * 128;

  // B staging: per wave 32 rows, 4 issues x (8 rows x 8 units)
  const bf16_t* gB = Wb + (size_t)(n0 + w * 32 + (lane >> 3)) * DIM + (((lane & 7) ^ (lane >> 3)) << 3);
  bf16_t* lB = Bs + (w * 32) * 64 + lane * 8;

  // A staging pointers (one set used per instantiation)
  const bf16_t* gAb = Xb + (size_t)(m0 + w * 32 + (lane >> 3)) * DIM + (((lane & 7) ^ (lane >> 3)) << 3);
  bf16_t* lAb = (bf16_t*)Abuf + (w * 32) * 64 + lane * 8;
  const int r4 = lane >> 4, uu = lane & 15;
  const float* gA0 = X + (size_t)(m0 + w * 32 + r4) * DIM + ((uu ^ r4) << 2);
  const float* gA1 = X + (size_t)(m0 + w * 32 + r4) * DIM + ((uu ^ (4 | r4)) << 2);
  float* lAf = (float*)Abuf + (w * 32) * 64 + lane * 4;

  floatx4 acc[4][4];
#pragma unroll
  for (int i = 0; i < 4; ++i)
#pragma unroll
    for (int j = 0; j < 4; ++j) acc[i][j] = (floatx4){0.f, 0.f, 0.f, 0.f};

  for (int kt = 0; kt < DIM; kt += 64) {
    if constexpr (XB) {
#pragma unroll
      for (int i = 0; i < 4; ++i) gll16(gAb + i * 8 * DIM, lAb + i * 8 * 64);
      gAb += 64;
    } else {
#pragma unroll
      for (int i = 0; i < 8; ++i) {
        const float* s = ((i & 1) ? gA1 : gA0) + i * 4 * DIM;
        gll16(s, lAf + i * 4 * 64);
      }
      gA0 += 64; gA1 += 64;
    }
#pragma unroll
    for (int i = 0; i < 4; ++i) gll16(gB + i * 8 * DIM, lB + i * 8 * 64);
    gB += 64;
    __syncthreads();
#pragma unroll
    for (int kk = 0; kk < 2; ++kk) {
      bf16x8 af[4], bfr[4];
#pragma unroll
      for (int f = 0; f < 4; ++f) {
        int ar = wr * 64 + f * 16 + l15;
        if constexpr (XB) {
          int ua = (kk * 4 + l4) ^ (l15 & 7);
          af[f] = *(const bf16x8*)((const bf16_t*)Abuf + ar * 64 + ua * 8);
        } else {
          int u0 = (kk * 8 + l4 * 2) ^ (l15 & 7);
          int u1 = (kk * 8 + l4 * 2 + 1) ^ (l15 & 7);
          float4 a0 = *(const float4*)((const float*)Abuf + ar * 64 + u0 * 4);
          float4 a1 = *(const float4*)((const float*)Abuf + ar * 64 + u1 * 4);
          bf16x8 t;
          t[0] = (bf16_t)a0.x; t[1] = (bf16_t)a0.y; t[2] = (bf16_t)a0.z; t[3] = (bf16_t)a0.w;
          t[4] = (bf16_t)a1.x; t[5] = (bf16_t)a1.y; t[6] = (bf16_t)a1.z; t[7] = (bf16_t)a1.w;
          af[f] = t;
        }
        int br = wc * 64 + f * 16 + l15;
        int ub = (kk * 4 + l4) ^ (l15 & 7);
        bfr[f] = *(const bf16x8*)(Bs + br * 64 + ub * 8);
      }
#pragma unroll
      for (int i = 0; i < 4; ++i)
#pragma unroll
        for (int j = 0; j < 4; ++j)
          acc[i][j] = mfma_bf16(af[i], bfr[j], acc[i][j]);
    }
    __syncthreads();
  }

  const int colbase = n0 + wc * 64;
  if (n0 < 512) {
#pragma unroll
    for (int fm = 0; fm < 4; ++fm) {
#pragma unroll
      for (int r = 0; r < 4; ++r) {
        float v0 = acc[fm][0][r], v1 = acc[fm][1][r], v2 = acc[fm][2][r], v3 = acc[fm][3][r];
        float mx = fmaxf(fmaxf(v0, v1), fmaxf(v2, v3));
        mx = fmaxf(mx, __shfl_xor(mx, 1));
        mx = fmaxf(mx, __shfl_xor(mx, 2));
        mx = fmaxf(mx, __shfl_xor(mx, 4));
        mx = fmaxf(mx, __shfl_xor(mx, 8));
        float e0 = __expf(v0 - mx), e1 = __expf(v1 - mx), e2 = __expf(v2 - mx), e3 = __expf(v3 - mx);
        float s = e0 + e1 + e2 + e3;
        s += __shfl_xor(s, 1); s += __shfl_xor(s, 2); s += __shfl_xor(s, 4); s += __shfl_xor(s, 8);
        float inv = 0.125f / s;
        int m = m0 + wr * 64 + fm * 16 + l4 * 4 + r;
        bf16_t* rowp = qs + (size_t)m * DIM + colbase;
        rowp[l15]      = (bf16_t)(e0 * inv);
        rowp[16 + l15] = (bf16_t)(e1 * inv);
        rowp[32 + l15] = (bf16_t)(e2 * inv);
        rowp[48 + l15] = (bf16_t)(e3 * inv);
      }
    }
  } else if (n0 < 1024) {
    const int cb = colbase - 512;
    float c0 = 0.f, c1 = 0.f, c2 = 0.f, c3 = 0.f;
#pragma unroll
    for (int fm = 0; fm < 4; ++fm) {
#pragma unroll
      for (int r = 0; r < 4; ++r) {
        int m = m0 + wr * 64 + fm * 16 + l4 * 4 + r;
        bf16_t* rowp = ek + (size_t)m * DIM + cb;
        float e0 = __expf(acc[fm][0][r]);
        float e1 = __expf(acc[fm][1][r]);
        float e2 = __expf(acc[fm][2][r]);
        float e3 = __expf(acc[fm][3][r]);
        rowp[l15]      = (bf16_t)e0;
        rowp[16 + l15] = (bf16_t)e1;
        rowp[32 + l15] = (bf16_t)e2;
        rowp[48 + l15] = (bf16_t)e3;
        c0 += e0; c1 += e1; c2 += e2; c3 += e3;
      }
    }
    c0 += __shfl_xor(c0, 16); c0 += __shfl_xor(c0, 32);
    c1 += __shfl_xor(c1, 16); c1 += __shfl_xor(c1, 32);
    c2 += __shfl_xor(c2, 16); c2 += __shfl_xor(c2, 32);
    c3 += __shfl_xor(c3, 16); c3 += __shfl_xor(c3, 32);
    if (lane < 16) {
      int b = m0 >> 12;
      atomicAdd(&S[b * 512 + cb + lane],      c0);
      atomicAdd(&S[b * 512 + cb + 16 + lane], c1);
      atomicAdd(&S[b * 512 + cb + 32 + lane], c2);
      atomicAdd(&S[b * 512 + cb + 48 + lane], c3);
    }
  } else {
    const int cb = colbase - 1024;
#pragma unroll
    for (int fm = 0; fm < 4; ++fm) {
#pragma unroll
      for (int r = 0; r < 4; ++r) {
        int m = m0 + wr * 64 + fm * 16 + l4 * 4 + r;
        bf16_t* rowp = vb + (size_t)m * DIM + cb;
        rowp[l15]      = (bf16_t)acc[fm][0][r];
        rowp[16 + l15] = (bf16_t)acc[fm][1][r];
        rowp[32 + l15] = (bf16_t)acc[fm][2][r];
        rowp[48 + l15] = (bf16_t)acc[fm][3][r];
      }
    }
  }
}

// ---------------- K2: ctxpart[b,h,chunk] = ek_chunk^T @ v_chunk (64x64) ----------------
#define TP 136
__global__ __launch_bounds__(256) void k_ctx(const bf16_t* __restrict__ ek,
                                             const bf16_t* __restrict__ vb,
                                             float* __restrict__ ctxpart) {
  __shared__ __align__(16) bf16_t ekT[64 * TP];
  __shared__ __align__(16) bf16_t vT[64 * TP];
  __shared__ float red[4096];
  const int tid = threadIdx.x;
  const int lane = tid & 63, wid = tid >> 6;
  const int l15 = lane & 15, l4 = lane >> 4;
  const int bh = blockIdx.x, chunk = blockIdx.y;
  const int b = bh >> 3, h = bh & 7;
  const int base = b * SEQ + chunk * 512;

  floatx4 acc[4][4];
#pragma unroll
  for (int i = 0; i < 4; ++i)
#pragma unroll
    for (int j = 0; j < 4; ++j) acc[i][j] = (floatx4){0.f, 0.f, 0.f, 0.f};

  for (int nt = 0; nt < 4; ++nt) {
    const int n0 = base + nt * 128;
#pragma unroll
    for (int i = 0; i < 4; ++i) {
      int q = tid + i * 256;
      int n = q & 127;
      int c8 = (q >> 7) << 3;
      bf16x8 vk = *(const bf16x8*)&ek[(size_t)(n0 + n) * DIM + h * 64 + c8];
      bf16x8 vv = *(const bf16x8*)&vb[(size_t)(n0 + n) * DIM + h * 64 + c8];
#pragma unroll
      for (int j = 0; j < 8; ++j) {
        ekT[(c8 + j) * TP + n] = vk[j];
        vT [(c8 + j) * TP + n] = vv[j];
      }
    }
    __syncthreads();
    const int nb = wid * 32;
    bf16x8 af[4], bfr[4];
#pragma unroll
    for (int f = 0; f < 4; ++f) {
      af[f]  = *(const bf16x8*)&ekT[(f * 16 + l15) * TP + nb + l4 * 8];
      bfr[f] = *(const bf16x8*)&vT [(f * 16 + l15) * TP + nb + l4 * 8];
    }
#pragma unroll
    for (int i = 0; i < 4; ++i)
#pragma unroll
      for (int j = 0; j < 4; ++j)
        acc[i][j] = mfma_bf16(af[i], bfr[j], acc[i][j]);
    __syncthreads();
  }

  for (int w = 0; w < 4; ++w) {
    if (wid == w) {
#pragma unroll
      for (int fm = 0; fm < 4; ++fm)
#pragma unroll
        for (int fn = 0; fn < 4; ++fn)
#pragma unroll
          for (int r = 0; r < 4; ++r) {
            int d = fm * 16 + l4 * 4 + r;
            int e = fn * 16 + l15;
            if (w == 0) red[d * 64 + e] = acc[fm][fn][r];
            else        red[d * 64 + e] += acc[fm][fn][r];
          }
    }
    __syncthreads();
  }
  float* dst = ctxpart + ((size_t)bh * 8 + chunk) * 4096;
#pragma unroll
  for (int i = 0; i < 4; ++i) {
    int q = tid + i * 256;
    *(float4*)&dst[q * 4] = *(const float4*)&red[q * 4];
  }
}

// ---------------- K3a: reduce partials + divide by column sums ----------------
__global__ __launch_bounds__(256) void k_ctxred(const float* __restrict__ ctxpart,
                                                const float* __restrict__ S,
                                                float* __restrict__ ctx) {
  int bh = blockIdx.x;
  int idx = blockIdx.y * 256 + threadIdx.x;
  int b = bh >> 3, h = bh & 7;
  float s = 0.f;
#pragma unroll
  for (int p = 0; p < 8; ++p) s += ctxpart[((size_t)bh * 8 + p) * 4096 + idx];
  int d = idx >> 6;
  ctx[(size_t)bh * 4096 + idx] = s / S[b * 512 + h * 64 + d];
}

// ---------------- K3b: Mt[b][dcol][h*64+d] = sum_e ctx[b,h,d,e]*w_out[dcol,h*64+e] ----------------
__global__ __launch_bounds__(128) void k_mt(const float* __restrict__ ctx,
                                            const float* __restrict__ w_out,
                                            bf16_t* __restrict__ Mt) {
  __shared__ float cs[4096];
  const int tid = threadIdx.x;
  const int b = blockIdx.x, h = blockIdx.y, dq = blockIdx.z;
#pragma unroll
  for (int i = 0; i < 8; ++i) {
    int q = tid + i * 128;
    *(float4*)&cs[q * 4] = *(const float4*)&ctx[((size_t)(b * 8 + h)) * 4096 + q * 4];
  }
  __syncthreads();
  const int dcol = dq * 128 + tid;
  float a[64];
#pragma unroll
  for (int d = 0; d < 64; ++d) a[d] = 0.f;
  for (int e = 0; e < 64; ++e) {
    float we = w_out[(size_t)dcol * 512 + h * 64 + e];
#pragma unroll
    for (int d = 0; d < 64; ++d) a[d] += cs[d * 64 + e] * we;
  }
  bf16_t* dst = Mt + ((size_t)b * 512 + dcol) * 512 + h * 64;
#pragma unroll
  for (int g = 0; g < 8; ++g) {
    bf16x8 o;
#pragma unroll
    for (int j = 0; j < 8; ++j) o[j] = (bf16_t)a[g * 8 + j];
    *(bf16x8*)&dst[g * 8] = o;
  }
}

// ---------------- K4: out2b[b] = qs[b] @ Mt[b]  (BK=64, gll, swizzled; bf16 out) ----------------
__global__ __launch_bounds__(256) void k_out(const bf16_t* __restrict__ qs,
                                             const bf16_t* __restrict__ Mt,
                                             bf16_t* __restrict__ out2b) {
  __shared__ __align__(16) bf16_t As[128 * 64];
  __shared__ __align__(16) bf16_t Bs[128 * 64];
  const int tid = threadIdx.x;
  const int lane = tid & 63, w = tid >> 6;
  const int wr = w >> 1, wc = w & 1;
  const int l15 = lane & 15, l4 = lane >> 4;
  const int m0 = blockIdx.x * 128;
  const int n0 = blockIdx.y * 128;
  const bf16_t* Bp = Mt + (size_t)(blockIdx.x >> 5) * 512 * 512;

  const bf16_t* gA = qs + (size_t)(m0 + w * 32 + (lane >> 3)) * 512 + (((lane & 7) ^ (lane >> 3)) << 3);
  const bf16_t* gB = Bp + (size_t)(n0 + w * 32 + (lane >> 3)) * 512 + (((lane & 7) ^ (lane >> 3)) << 3);
  bf16_t* lA = As + (w * 32) * 64 + lane * 8;
  bf16_t* lB = Bs + (w * 32) * 64 + lane * 8;

  floatx4 acc[4][4];
#pragma unroll
  for (int i = 0; i < 4; ++i)
#pragma unroll
    for (int j = 0; j < 4; ++j) acc[i][j] = (floatx4){0.f, 0.f, 0.f, 0.f};

  for (int kt = 0; kt < 512; kt += 64) {
#pragma unroll
    for (int i = 0; i < 4; ++i) {
      gll16(gA + i * 8 * 512, lA + i * 8 * 64);
      gll16(gB + i * 8 * 512, lB + i * 8 * 64);
    }
    gA += 64; gB += 64;
    __syncthreads();
#pragma unroll
    for (int kk = 0; kk < 2; ++kk) {
      bf16x8 af[4], bfr[4];
#pragma unroll
      for (int f = 0; f < 4; ++f) {
        int ar = wr * 64 + f * 16 + l15;
        int ua = (kk * 4 + l4) ^ (l15 & 7);
        af[f] = *(const bf16x8*)(As + ar * 64 + ua * 8);
        int br = wc * 64 + f * 16 + l15;
        int ub = (kk * 4 + l4) ^ (l15 & 7);
        bfr[f] = *(const bf16x8*)(Bs + br * 64 + ub * 8);
      }
#pragma unroll
      for (int i = 0; i < 4; ++i)
#pragma unroll
        for (int j = 0; j < 4; ++j)
          acc[i][j] = mfma_bf16(af[i], bfr[j], acc[i][j]);
    }
    __syncthreads();
  }
#pragma unroll
  for (int fm = 0; fm < 4; ++fm) {
#pragma unroll
    for (int r = 0; r < 4; ++r) {
      int m = m0 + wr * 64 + fm * 16 + l4 * 4 + r;
      bf16_t* rowp = out2b + (size_t)m * 512 + n0 + wc * 64;
      rowp[l15]      = (bf16_t)acc[fm][0][r];
      rowp[16 + l15] = (bf16_t)acc[fm][1][r];
      rowp[32 + l15] = (bf16_t)acc[fm][2][r];
      rowp[48 + l15] = (bf16_t)acc[fm][3][r];
    }
  }
}

// ---------------- K5: gamma LayerNorm (bf16 in, fp32 out), wave per row ----------------
__global__ __launch_bounds__(256) void k_ln(const bf16_t* __restrict__ out2b,
                                            const float* __restrict__ gamma,
                                            float* __restrict__ out) {
  const int lane = threadIdx.x & 63;
  const int row = blockIdx.x * 4 + (threadIdx.x >> 6);
  bf16x8 v = *(const bf16x8*)(out2b + (size_t)row * 512 + lane * 8);
  float f[8];
#pragma unroll
  for (int j = 0; j < 8; ++j) f[j] = (float)v[j];
  float s = 0.f, q = 0.f;
#pragma unroll
  for (int j = 0; j < 8; ++j) { s += f[j]; q += f[j] * f[j]; }
#pragma unroll
  for (int m = 1; m <= 32; m <<= 1) { s += __shfl_xor(s, m); q += __shfl_xor(q, m); }
  float mean = s * (1.f / 512.f);
  float var = q * (1.f / 512.f) - mean * mean;
  float rstd = rsqrtf(var + 1e-5f);
  float4 g0 = ((const float4*)gamma)[lane * 2];
  float4 g1 = ((const float4*)gamma)[lane * 2 + 1];
  float4 o0, o1;
  o0.x = (f[0] - mean) * rstd * g0.x;
  o0.y = (f[1] - mean) * rstd * g0.y;
  o0.z = (f[2] - mean) * rstd * g0.z;
  o0.w = (f[3] - mean) * rstd * g0.w;
  o1.x = (f[4] - mean) * rstd * g1.x;
  o1.y = (f[5] - mean) * rstd * g1.y;
  o1.z = (f[6] - mean) * rstd * g1.z;
  o1.w = (f[7] - mean) * rstd * g1.w;
  float* y = out + (size_t)row * 512;
  ((float4*)y)[lane * 2]     = o0;
  ((float4*)y)[lane * 2 + 1] = o1;
}

extern "C" void kernel_launch(void* const* d_in, const int* in_sizes, int n_in,
                              void* d_out, int out_size, void* d_ws, size_t ws_size,
                              hipStream_t stream) {
  const float* x     = (const float*)d_in[0];
  const float* w_qkv = (const float*)d_in[1];
  const float* w_out = (const float*)d_in[2];
  const float* gamma = (const float*)d_in[3];
  float* out = (float*)d_out;
  char* ws = (char*)d_ws;

  bf16_t* qs      = (bf16_t*)(ws);                       // 33,554,432
  bf16_t* ek      = (bf16_t*)(ws + 33554432);            // 33,554,432
  bf16_t* vb      = (bf16_t*)(ws + 67108864);            // 33,554,432
  bf16_t* wqkvb   = (bf16_t*)(ws + 100663296);           //  1,572,864
  float*  S       = (float*)(ws + 102236160);            //     16,384
  bf16_t* Xb      = (bf16_t*)(ws + 102252544);           // 33,554,432 (dead after k_qkv)
  float*  ctx     = (float*)(ws + 102252544);            // alias Xb (written post-k_qkv)
  float*  ctxpart = (float*)(ws + 103301120);            // alias Xb region
  bf16_t* Mt      = (bf16_t*)(ws + 111689728);           // alias Xb region
  bf16_t* out2b   = (bf16_t*)(ws + 33554432);            // alias ek (dead after k_ctx)

  const bool big = ws_size >= (size_t)135806976;  // Xb end

  hipMemsetAsync(S, 0, BATCH * 512 * sizeof(float), stream);

  k_cvt<<<384, 256, 0, stream>>>(w_qkv, wqkvb);

  dim3 g1(256, 12);
  if (big) {
    // x: 8*4096*512 = 16,777,216 elems; 2048 elems/block -> 8192 blocks (NOT 16384 — r4 OOB crash)
    k_cvt<<<8192, 256, 0, stream>>>(x, Xb);
    k_qkv<true><<<g1, 256, 0, stream>>>(x, Xb, wqkvb, qs, ek, vb, S);
  } else {
    k_qkv<false><<<g1, 256, 0, stream>>>(x, (const bf16_t*)nullptr, wqkvb, qs, ek, vb, S);
  }

  dim3 g2(64, 8);
  k_ctx<<<g2, 256, 0, stream>>>(ek, vb, ctxpart);

  dim3 g3(64, 16);
  k_ctxred<<<g3, 256, 0, stream>>>(ctxpart, S, ctx);

  dim3 g4(8, 8, 4);
  k_mt<<<g4, 128, 0, stream>>>(ctx, w_out, Mt);

  dim3 g5(256, 4);
  k_out<<<g5, 256, 0, stream>>>(qs, Mt, out2b);

  k_ln<<<8192, 256, 0, stream>>>(out2b, gamma, out);
}